// Round 4
// baseline (682.855 us; speedup 1.0000x reference)
//
#include <hip/hip_runtime.h>

#define TOK 49
#define DIM 128
#define NHEAD 4
#define NWIN 1024
#define SCALE 0.17677669529663687f  // 1/sqrt(32)

typedef __bf16 bf16x8 __attribute__((ext_vector_type(8)));
typedef short s16x4 __attribute__((ext_vector_type(4)));
typedef float f32x4 __attribute__((ext_vector_type(4)));
typedef unsigned short u16;
typedef unsigned int u32;

// 16x16x16 bf16 MFMA: A/B frag k-index = (lane>>4)*4 + j == C-frag row layout
// ((lane>>4)*4 + reg), so chained-MFMA operands pack lane-locally from the
// previous accumulator. Builtin name has no underscore before "bf16".
#if defined(__HIP_DEVICE_COMPILE__)
#define MFMA16(a, b, c) __builtin_amdgcn_mfma_f32_16x16x16bf16_1k(a, b, c, 0, 0, 0)
#define MFMA32(a, b, c) __builtin_amdgcn_mfma_f32_16x16x32_bf16(a, b, c, 0, 0, 0)
#else
// host pass: parse-only stubs (never executed)
__device__ inline f32x4 MFMA16(s16x4, s16x4, f32x4 c) { return c; }
__device__ inline f32x4 MFMA32(bf16x8, bf16x8, f32x4 c) { return c; }
#endif

__device__ __forceinline__ int xo256(int row, int kbyte) {
    return row * 256 + (kbyte ^ ((row & 7) << 4));
}
__device__ __forceinline__ u16 bfbits(float x) {
    __bf16 t = (__bf16)x;
    return __builtin_bit_cast(u16, t);
}
__device__ __forceinline__ float bf2f(u16 x) {
    u32 u = ((u32)x) << 16;
    return __builtin_bit_cast(float, u);
}
__device__ __forceinline__ bf16x8 cvt8(const float* __restrict__ p) {
    float4 a = *reinterpret_cast<const float4*>(p);
    float4 bq = *reinterpret_cast<const float4*>(p + 4);
    bf16x8 r;
    r[0] = (__bf16)a.x; r[1] = (__bf16)a.y; r[2] = (__bf16)a.z; r[3] = (__bf16)a.w;
    r[4] = (__bf16)bq.x; r[5] = (__bf16)bq.y; r[6] = (__bf16)bq.z; r[7] = (__bf16)bq.w;
    return r;
}
__device__ __forceinline__ bf16x8 cvt8s(const float* __restrict__ p, float s) {
    float4 a = *reinterpret_cast<const float4*>(p);
    float4 bq = *reinterpret_cast<const float4*>(p + 4);
    bf16x8 r;
    r[0] = (__bf16)(a.x * s); r[1] = (__bf16)(a.y * s);
    r[2] = (__bf16)(a.z * s); r[3] = (__bf16)(a.w * s);
    r[4] = (__bf16)(bq.x * s); r[5] = (__bf16)(bq.y * s);
    r[6] = (__bf16)(bq.z * s); r[7] = (__bf16)(bq.w * s);
    return r;
}
__device__ __forceinline__ s16x4 pack4(const f32x4& a) {
    s16x4 r;
    r[0] = (short)bfbits(a[0]); r[1] = (short)bfbits(a[1]);
    r[2] = (short)bfbits(a[2]); r[3] = (short)bfbits(a[3]);
    return r;
}

// mask table: [NWIN][64][64] bf16 (zero-padded) -> aligned uint2 reads in softmax
__global__ void mask_pre_kernel(const float* __restrict__ mask, u16* __restrict__ tbl) {
    const int idx = blockIdx.x * 256 + threadIdx.x;  // exactly NWIN*64*64
    const int w = idx >> 12, l = (idx >> 6) & 63, m = idx & 63;
    u16 v = 0;
    if (l < TOK && m < TOK) v = bfbits(mask[(w * TOK + l) * TOK + m]);
    tbl[idx] = v;
}

// bias table: [NHEAD][64][64] f32 (zero-padded) -> aligned float4 reads
__global__ void bias_pre_kernel(const float* __restrict__ rel, float* __restrict__ biasT) {
    const int idx = blockIdx.x * 256 + threadIdx.x;  // exactly NHEAD*64*64
    const int h = idx >> 12, l = (idx >> 6) & 63, m = idx & 63;
    float v = 0.0f;
    if (l < TOK && m < TOK) {
        const int dl = l / 7 - m / 7 + 6;
        const int dc = l % 7 - m % 7 + 6;
        v = rel[(dl * 13 + dc) * NHEAD + h];
    }
    biasT[idx] = v;
}

template <int MODE>  // 0: mask from ws table; 1: mask direct from global
__global__ __launch_bounds__(256, 4) void winattn_kernel(
    const float* __restrict__ q, const float* __restrict__ k, const float* __restrict__ v,
    const float* __restrict__ mask, const float* __restrict__ Wq, const float* __restrict__ Wk,
    const float* __restrict__ Wv, const float* __restrict__ Wo, const float* __restrict__ bo,
    const u16* __restrict__ mtbl, const float* __restrict__ btbl, float* __restrict__ out)
{
    __shared__ __align__(16) char OH[16384];  // [64 l][128 d] bf16, xo256-swizzled
    const int tid = threadIdx.x;
    const int wave = tid >> 6;
    const int lane = tid & 63;
    const int l16 = lane & 15;
    const int k8 = lane >> 4;
    const int b = blockIdx.x;
    const int h = wave;  // wave == head

    const float* qp = q + (size_t)b * (TOK * DIM);
    const float* kp = k + (size_t)b * (TOK * DIM);
    const float* vp = v + (size_t)b * (TOK * DIM);
    float* op = out + (size_t)b * (TOK * DIM);

    // ---- Q^T / K^T projections, swapped (W . X^T), C rows = d ----
    // A = W-frag: row = h*32 + t*16 + l16, k = kk*32 + k8*8 + j
    // B = X^T-frag: col = tok = ni*16 + l16 (clamped), k same -> 32B contiguous loads
    s16x4 qf[2][4], kf[2][4];  // x16 frags: [d-chunk t][tok-tile]
    {
        f32x4 acc[2][4];
        #pragma unroll
        for (int t = 0; t < 2; ++t)
            #pragma unroll
            for (int ni = 0; ni < 4; ++ni) acc[t][ni] = f32x4{0.f, 0.f, 0.f, 0.f};
        #pragma unroll
        for (int kk = 0; kk < 4; ++kk) {
            bf16x8 wa[2];
            #pragma unroll
            for (int t = 0; t < 2; ++t)
                wa[t] = cvt8s(Wq + (h * 32 + t * 16 + l16) * DIM + kk * 32 + k8 * 8, SCALE);
            bf16x8 xb[4];
            #pragma unroll
            for (int ni = 0; ni < 4; ++ni) {
                int tok = ni * 16 + l16; tok = tok < TOK ? tok : TOK - 1;
                xb[ni] = cvt8(qp + tok * DIM + kk * 32 + k8 * 8);
            }
            #pragma unroll
            for (int t = 0; t < 2; ++t)
                #pragma unroll
                for (int ni = 0; ni < 4; ++ni) acc[t][ni] = MFMA32(wa[t], xb[ni], acc[t][ni]);
        }
        #pragma unroll
        for (int t = 0; t < 2; ++t)
            #pragma unroll
            for (int ni = 0; ni < 4; ++ni) qf[t][ni] = pack4(acc[t][ni]);

        #pragma unroll
        for (int t = 0; t < 2; ++t)
            #pragma unroll
            for (int ni = 0; ni < 4; ++ni) acc[t][ni] = f32x4{0.f, 0.f, 0.f, 0.f};
        #pragma unroll
        for (int kk = 0; kk < 4; ++kk) {
            bf16x8 wa[2];
            #pragma unroll
            for (int t = 0; t < 2; ++t)
                wa[t] = cvt8(Wk + (h * 32 + t * 16 + l16) * DIM + kk * 32 + k8 * 8);
            bf16x8 xb[4];
            #pragma unroll
            for (int ni = 0; ni < 4; ++ni) {
                int tok = ni * 16 + l16; tok = tok < TOK ? tok : TOK - 1;
                xb[ni] = cvt8(kp + tok * DIM + kk * 32 + k8 * 8);
            }
            #pragma unroll
            for (int t = 0; t < 2; ++t)
                #pragma unroll
                for (int ni = 0; ni < 4; ++ni) acc[t][ni] = MFMA32(wa[t], xb[ni], acc[t][ni]);
        }
        #pragma unroll
        for (int t = 0; t < 2; ++t)
            #pragma unroll
            for (int ni = 0; ni < 4; ++ni) kf[t][ni] = pack4(acc[t][ni]);
    }

    // ---- V projection, standard (X . Wv^T), C rows = tok = m ----
    s16x4 vf[4][2];  // [m-chunk][d-tile n]
    {
        f32x4 acc[4][2];
        #pragma unroll
        for (int mi = 0; mi < 4; ++mi)
            #pragma unroll
            for (int n = 0; n < 2; ++n) acc[mi][n] = f32x4{0.f, 0.f, 0.f, 0.f};
        #pragma unroll
        for (int kk = 0; kk < 4; ++kk) {
            bf16x8 xa[4];
            #pragma unroll
            for (int mi = 0; mi < 4; ++mi) {
                int tok = mi * 16 + l16; tok = tok < TOK ? tok : TOK - 1;
                xa[mi] = cvt8(vp + tok * DIM + kk * 32 + k8 * 8);
            }
            bf16x8 wb[2];
            #pragma unroll
            for (int n = 0; n < 2; ++n)
                wb[n] = cvt8(Wv + (h * 32 + n * 16 + l16) * DIM + kk * 32 + k8 * 8);
            #pragma unroll
            for (int mi = 0; mi < 4; ++mi)
                #pragma unroll
                for (int n = 0; n < 2; ++n) acc[mi][n] = MFMA32(xa[mi], wb[n], acc[mi][n]);
        }
        #pragma unroll
        for (int mi = 0; mi < 4; ++mi)
            #pragma unroll
            for (int n = 0; n < 2; ++n) vf[mi][n] = pack4(acc[mi][n]);
    }

    // ---- QK^T via MFMA16: E^T[m][l] = sum_d kh[m][d] qh[l][d] (scale folded in Wq) ----
    f32x4 e[4][4];  // C: row = m = mi*16 + k8*4 + r, col = l = ni*16 + l16
    #pragma unroll
    for (int mi = 0; mi < 4; ++mi) {
        #pragma unroll
        for (int ni = 0; ni < 4; ++ni) {
            f32x4 c = {0.f, 0.f, 0.f, 0.f};
            c = MFMA16(kf[0][mi], qf[0][ni], c);
            e[mi][ni] = MFMA16(kf[1][mi], qf[1][ni], c);
        }
    }

    // ---- bias + mask + softmax over m (in registers) ----
    {
        const float* brow = btbl + ((size_t)h << 12);
        const u16* mrow = (MODE == 0) ? mtbl + ((size_t)(b & (NWIN - 1)) << 12) : nullptr;
        const float* mp = mask + (size_t)(b & (NWIN - 1)) * (TOK * TOK);
        #pragma unroll
        for (int ni = 0; ni < 4; ++ni) {
            const int l = ni * 16 + l16;
            const bool lv = l < TOK;
            #pragma unroll
            for (int mi = 0; mi < 4; ++mi) {
                const int m0 = mi * 16 + k8 * 4;
                const float4 bg = *reinterpret_cast<const float4*>(brow + l * 64 + m0);
                const float bgv[4] = {bg.x, bg.y, bg.z, bg.w};
                float mkf[4];
                if constexpr (MODE == 0) {
                    const uint2 mraw = *reinterpret_cast<const uint2*>(mrow + l * 64 + m0);
                    mkf[0] = bf2f((u16)(mraw.x & 0xffffu));
                    mkf[1] = bf2f((u16)(mraw.x >> 16));
                    mkf[2] = bf2f((u16)(mraw.y & 0xffffu));
                    mkf[3] = bf2f((u16)(mraw.y >> 16));
                } else {
                    #pragma unroll
                    for (int r = 0; r < 4; ++r) {
                        const int m = m0 + r;
                        mkf[r] = (lv && m < TOK) ? mp[l * TOK + m] : 0.0f;
                    }
                }
                #pragma unroll
                for (int r = 0; r < 4; ++r) {
                    const int m = m0 + r;
                    float val = -1e30f;
                    if (lv && m < TOK) val = e[mi][ni][r] + bgv[r] + mkf[r];
                    e[mi][ni][r] = val;
                }
            }
            float mx = -1e30f;
            #pragma unroll
            for (int mi = 0; mi < 4; ++mi)
                #pragma unroll
                for (int r = 0; r < 4; ++r) mx = fmaxf(mx, e[mi][ni][r]);
            mx = fmaxf(mx, __shfl_xor(mx, 16));
            mx = fmaxf(mx, __shfl_xor(mx, 32));
            float s = 0.f;
            #pragma unroll
            for (int mi = 0; mi < 4; ++mi) {
                #pragma unroll
                for (int r = 0; r < 4; ++r) {
                    const float p = __expf(e[mi][ni][r] - mx);
                    e[mi][ni][r] = p;
                    s += p;
                }
            }
            s += __shfl_xor(s, 16);
            s += __shfl_xor(s, 32);
            const float rs = 1.0f / s;
            #pragma unroll
            for (int mi = 0; mi < 4; ++mi)
                #pragma unroll
                for (int r = 0; r < 4; ++r) e[mi][ni][r] *= rs;
        }
    }

    // ---- PV via MFMA16: O[l][d] = sum_m P[l][m] V[m][d]; all frags lane-local ----
    f32x4 o_[4][2];  // C: row = l = ni*16 + k8*4 + r, col = d = h*32 + n*16 + l16
    #pragma unroll
    for (int ni = 0; ni < 4; ++ni) {
        s16x4 pf[4];
        #pragma unroll
        for (int mi = 0; mi < 4; ++mi) pf[mi] = pack4(e[mi][ni]);
        #pragma unroll
        for (int n = 0; n < 2; ++n) {
            f32x4 c = {0.f, 0.f, 0.f, 0.f};
            #pragma unroll
            for (int mi = 0; mi < 4; ++mi) c = MFMA16(pf[mi], vf[mi][n], c);
            o_[ni][n] = c;
        }
    }

    // hoist Wo A-frags (independent of LDS)
    bf16x8 aw[2][4];
    #pragma unroll
    for (int m2 = 0; m2 < 2; ++m2) {
        const int o = (wave * 2 + m2) * 16 + l16;
        #pragma unroll
        for (int kk = 0; kk < 4; ++kk)
            aw[m2][kk] = cvt8(Wo + o * DIM + kk * 32 + k8 * 8);
    }

    // ---- OH[l][d] <- O (scalar u16, swizzled); the ONLY barrier ----
    #pragma unroll
    for (int ni = 0; ni < 4; ++ni) {
        #pragma unroll
        for (int n = 0; n < 2; ++n) {
            const int d = h * 32 + n * 16 + l16;
            #pragma unroll
            for (int r = 0; r < 4; ++r) {
                const int row = ni * 16 + k8 * 4 + r;
                *reinterpret_cast<u16*>(OH + xo256(row, d * 2)) = bfbits(o_[ni][n][r]);
            }
        }
    }
    __syncthreads();

    // ---- output projection, swapped: out^T[o][l] = sum_i Wo[o][i] OH[l][i] ----
    #pragma unroll
    for (int ni = 0; ni < 4; ++ni) {
        const int l = ni * 16 + l16;
        bf16x8 bx[4];
        #pragma unroll
        for (int kk = 0; kk < 4; ++kk)
            bx[kk] = *reinterpret_cast<const bf16x8*>(OH + xo256(l, kk * 64 + k8 * 16));
        #pragma unroll
        for (int m2 = 0; m2 < 2; ++m2) {
            f32x4 c = {0.f, 0.f, 0.f, 0.f};
            #pragma unroll
            for (int kk = 0; kk < 4; ++kk) c = MFMA32(aw[m2][kk], bx[kk], c);
            if (l < TOK) {
                const int o0 = (wave * 2 + m2) * 16 + k8 * 4;
                const float4 bias = *reinterpret_cast<const float4*>(bo + o0);
                float4 st;
                st.x = c[0] + bias.x;
                st.y = c[1] + bias.y;
                st.z = c[2] + bias.z;
                st.w = c[3] + bias.w;
                *reinterpret_cast<float4*>(op + l * DIM + o0) = st;
            }
        }
    }
}

extern "C" void kernel_launch(void* const* d_in, const int* in_sizes, int n_in,
                              void* d_out, int out_size, void* d_ws, size_t ws_size,
                              hipStream_t stream) {
    const float* q    = (const float*)d_in[0];
    const float* k    = (const float*)d_in[1];
    const float* v    = (const float*)d_in[2];
    const float* mask = (const float*)d_in[3];
    const float* Wq   = (const float*)d_in[4];
    const float* Wk   = (const float*)d_in[5];
    const float* Wv   = (const float*)d_in[6];
    const float* Wo   = (const float*)d_in[7];
    const float* bo   = (const float*)d_in[8];
    const float* rel  = (const float*)d_in[9];
    float* out = (float*)d_out;

    const int B = in_sizes[0] / (TOK * DIM);  // 8192 windows
    const size_t MASK_BYTES = (size_t)NWIN * 64 * 64 * sizeof(u16);    // 8388608
    const size_t BIAS_BYTES = (size_t)NHEAD * 64 * 64 * sizeof(float); // 65536

    if (ws_size >= MASK_BYTES + BIAS_BYTES) {
        u16* mtbl = (u16*)d_ws;
        float* btbl = (float*)((char*)d_ws + MASK_BYTES);
        mask_pre_kernel<<<dim3(NWIN * 64 * 64 / 256), dim3(256), 0, stream>>>(mask, mtbl);
        bias_pre_kernel<<<dim3(NHEAD * 64 * 64 / 256), dim3(256), 0, stream>>>(rel, btbl);
        winattn_kernel<0><<<dim3(B), dim3(256), 0, stream>>>(q, k, v, mask, Wq, Wk, Wv, Wo,
                                                             bo, mtbl, btbl, out);
    } else {
        float* btbl = (float*)d_ws;  // 64 KB, proven to fit
        bias_pre_kernel<<<dim3(NHEAD * 64 * 64 / 256), dim3(256), 0, stream>>>(rel, btbl);
        winattn_kernel<1><<<dim3(B), dim3(256), 0, stream>>>(q, k, v, mask, Wq, Wk, Wv, Wo,
                                                             bo, nullptr, btbl, out);
    }
}

// Round 5
// 643.865 us; speedup vs baseline: 1.0606x; 1.0606x over previous
//
#include <hip/hip_runtime.h>

#define TOK 49
#define DIM 128
#define NHEAD 4
#define NWIN 1024
#define SCALE 0.17677669529663687f  // 1/sqrt(32)

typedef __bf16 bf16x8 __attribute__((ext_vector_type(8)));
typedef short s16x4 __attribute__((ext_vector_type(4)));
typedef float f32x4 __attribute__((ext_vector_type(4)));
typedef unsigned short u16;
typedef unsigned int u32;

// 16x16x16 bf16 MFMA: A/B frag k-index = (lane>>4)*4 + j == C-frag row layout
// ((lane>>4)*4 + reg), so chained-MFMA operands pack lane-locally from the
// previous accumulator.
#if defined(__HIP_DEVICE_COMPILE__)
#define MFMA16(a, b, c) __builtin_amdgcn_mfma_f32_16x16x16bf16_1k(a, b, c, 0, 0, 0)
#define MFMA32(a, b, c) __builtin_amdgcn_mfma_f32_16x16x32_bf16(a, b, c, 0, 0, 0)
#else
// host pass: parse-only stubs (never executed)
__device__ inline f32x4 MFMA16(s16x4, s16x4, f32x4 c) { return c; }
__device__ inline f32x4 MFMA32(bf16x8, bf16x8, f32x4 c) { return c; }
#endif

__device__ __forceinline__ int xo256(int row, int kbyte) {
    return row * 256 + (kbyte ^ ((row & 7) << 4));
}
__device__ __forceinline__ u16 bfbits(float x) {
    __bf16 t = (__bf16)x;
    return __builtin_bit_cast(u16, t);
}
__device__ __forceinline__ float bf2f(u16 x) {
    u32 u = ((u32)x) << 16;
    return __builtin_bit_cast(float, u);
}
__device__ __forceinline__ bf16x8 cvt8(const float* __restrict__ p) {
    float4 a = *reinterpret_cast<const float4*>(p);
    float4 bq = *reinterpret_cast<const float4*>(p + 4);
    bf16x8 r;
    r[0] = (__bf16)a.x; r[1] = (__bf16)a.y; r[2] = (__bf16)a.z; r[3] = (__bf16)a.w;
    r[4] = (__bf16)bq.x; r[5] = (__bf16)bq.y; r[6] = (__bf16)bq.z; r[7] = (__bf16)bq.w;
    return r;
}
__device__ __forceinline__ bf16x8 cvt8s(const float* __restrict__ p, float s) {
    float4 a = *reinterpret_cast<const float4*>(p);
    float4 bq = *reinterpret_cast<const float4*>(p + 4);
    bf16x8 r;
    r[0] = (__bf16)(a.x * s); r[1] = (__bf16)(a.y * s);
    r[2] = (__bf16)(a.z * s); r[3] = (__bf16)(a.w * s);
    r[4] = (__bf16)(bq.x * s); r[5] = (__bf16)(bq.y * s);
    r[6] = (__bf16)(bq.z * s); r[7] = (__bf16)(bq.w * s);
    return r;
}
__device__ __forceinline__ s16x4 pack4(const f32x4& a) {
    s16x4 r;
    r[0] = (short)bfbits(a[0]); r[1] = (short)bfbits(a[1]);
    r[2] = (short)bfbits(a[2]); r[3] = (short)bfbits(a[3]);
    return r;
}
__device__ __forceinline__ s16x4 pack4s(const f32x4& a, float s) {
    s16x4 r;
    r[0] = (short)bfbits(a[0] * s); r[1] = (short)bfbits(a[1] * s);
    r[2] = (short)bfbits(a[2] * s); r[3] = (short)bfbits(a[3] * s);
    return r;
}

// mask table: [NWIN][64][64] bf16 (zero-padded) -> aligned uint2 reads in softmax
__global__ void mask_pre_kernel(const float* __restrict__ mask, u16* __restrict__ tbl) {
    const int idx = blockIdx.x * 256 + threadIdx.x;  // exactly NWIN*64*64
    const int w = idx >> 12, l = (idx >> 6) & 63, m = idx & 63;
    u16 v = 0;
    if (l < TOK && m < TOK) v = bfbits(mask[(w * TOK + l) * TOK + m]);
    tbl[idx] = v;
}

// bias table: [NHEAD][64][64] f32 (zero-padded) -> aligned float4 reads
__global__ void bias_pre_kernel(const float* __restrict__ rel, float* __restrict__ biasT) {
    const int idx = blockIdx.x * 256 + threadIdx.x;  // exactly NHEAD*64*64
    const int h = idx >> 12, l = (idx >> 6) & 63, m = idx & 63;
    float v = 0.0f;
    if (l < TOK && m < TOK) {
        const int dl = l / 7 - m / 7 + 6;
        const int dc = l % 7 - m % 7 + 6;
        v = rel[(dl * 13 + dc) * NHEAD + h];
    }
    biasT[idx] = v;
}

template <int MODE>  // 0: mask from ws table; 1: mask direct from global
__global__ __launch_bounds__(256, 4) void winattn_kernel(
    const float* __restrict__ q, const float* __restrict__ k, const float* __restrict__ v,
    const float* __restrict__ mask, const float* __restrict__ Wq, const float* __restrict__ Wk,
    const float* __restrict__ Wv, const float* __restrict__ Wo, const float* __restrict__ bo,
    const u16* __restrict__ mtbl, const float* __restrict__ btbl, float* __restrict__ out)
{
    __shared__ __align__(16) char OH[16384];  // [64 l][128 d] bf16, xo256-swizzled
    const int tid = threadIdx.x;
    const int wave = tid >> 6;
    const int lane = tid & 63;
    const int l16 = lane & 15;
    const int k8 = lane >> 4;
    const int b = blockIdx.x;
    const int h = wave;  // wave == head

    const float* qp = q + (size_t)b * (TOK * DIM);
    const float* kp = k + (size_t)b * (TOK * DIM);
    const float* vp = v + (size_t)b * (TOK * DIM);
    float* op = out + (size_t)b * (TOK * DIM);

    // ================= phase 1: Q^T projection (scale folded), pack qf =======
    // swapped (W . X^T), C rows = d. A = W-frag, B = X^T-frag (32B contiguous).
    s16x4 qf[2][4], kf[2][4];  // [d-chunk t][tok-tile]
    {
        f32x4 acc[2][4];
        #pragma unroll
        for (int t = 0; t < 2; ++t)
            #pragma unroll
            for (int ni = 0; ni < 4; ++ni) acc[t][ni] = f32x4{0.f, 0.f, 0.f, 0.f};
        #pragma unroll
        for (int kk = 0; kk < 4; ++kk) {
            bf16x8 wa[2];
            #pragma unroll
            for (int t = 0; t < 2; ++t)
                wa[t] = cvt8s(Wq + (h * 32 + t * 16 + l16) * DIM + kk * 32 + k8 * 8, SCALE);
            bf16x8 xb[4];
            #pragma unroll
            for (int ni = 0; ni < 4; ++ni) {
                int tok = ni * 16 + l16; tok = tok < TOK ? tok : TOK - 1;
                xb[ni] = cvt8(qp + tok * DIM + kk * 32 + k8 * 8);
            }
            #pragma unroll
            for (int t = 0; t < 2; ++t)
                #pragma unroll
                for (int ni = 0; ni < 4; ++ni) acc[t][ni] = MFMA32(wa[t], xb[ni], acc[t][ni]);
        }
        #pragma unroll
        for (int t = 0; t < 2; ++t)
            #pragma unroll
            for (int ni = 0; ni < 4; ++ni) qf[t][ni] = pack4(acc[t][ni]);
    }
    // ================= phase 2: K^T projection, pack kf ======================
    {
        f32x4 acc[2][4];
        #pragma unroll
        for (int t = 0; t < 2; ++t)
            #pragma unroll
            for (int ni = 0; ni < 4; ++ni) acc[t][ni] = f32x4{0.f, 0.f, 0.f, 0.f};
        #pragma unroll
        for (int kk = 0; kk < 4; ++kk) {
            bf16x8 wa[2];
            #pragma unroll
            for (int t = 0; t < 2; ++t)
                wa[t] = cvt8(Wk + (h * 32 + t * 16 + l16) * DIM + kk * 32 + k8 * 8);
            bf16x8 xb[4];
            #pragma unroll
            for (int ni = 0; ni < 4; ++ni) {
                int tok = ni * 16 + l16; tok = tok < TOK ? tok : TOK - 1;
                xb[ni] = cvt8(kp + tok * DIM + kk * 32 + k8 * 8);
            }
            #pragma unroll
            for (int t = 0; t < 2; ++t)
                #pragma unroll
                for (int ni = 0; ni < 4; ++ni) acc[t][ni] = MFMA32(wa[t], xb[ni], acc[t][ni]);
        }
        #pragma unroll
        for (int t = 0; t < 2; ++t)
            #pragma unroll
            for (int ni = 0; ni < 4; ++ni) kf[t][ni] = pack4(acc[t][ni]);
    }

    // ================= phase 3: QK^T via MFMA16 (lane-local chaining) ========
    f32x4 e[4][4];  // C: row = m = mi*16 + k8*4 + r, col = l = ni*16 + l16
    #pragma unroll
    for (int mi = 0; mi < 4; ++mi) {
        #pragma unroll
        for (int ni = 0; ni < 4; ++ni) {
            f32x4 c = {0.f, 0.f, 0.f, 0.f};
            c = MFMA16(kf[0][mi], qf[0][ni], c);
            e[mi][ni] = MFMA16(kf[1][mi], qf[1][ni], c);
        }
    }
    // qf/kf dead here.

    // ================= phase 4: bias + mask + softmax; pack P -> pf ==========
    s16x4 pf[4][4];  // [m-chunk mi][l-tile ni], bf16 P/rs — e dies at loop end
    {
        const float* brow = btbl + ((size_t)h << 12);
        const u16* mrow = (MODE == 0) ? mtbl + ((size_t)(b & (NWIN - 1)) << 12) : nullptr;
        const float* mp = mask + (size_t)(b & (NWIN - 1)) * (TOK * TOK);
        #pragma unroll
        for (int ni = 0; ni < 4; ++ni) {
            const int l = ni * 16 + l16;
            const bool lv = l < TOK;
            #pragma unroll
            for (int mi = 0; mi < 4; ++mi) {
                const int m0 = mi * 16 + k8 * 4;
                const float4 bg = *reinterpret_cast<const float4*>(brow + l * 64 + m0);
                const float bgv[4] = {bg.x, bg.y, bg.z, bg.w};
                float mkf[4];
                if constexpr (MODE == 0) {
                    const uint2 mraw = *reinterpret_cast<const uint2*>(mrow + l * 64 + m0);
                    mkf[0] = bf2f((u16)(mraw.x & 0xffffu));
                    mkf[1] = bf2f((u16)(mraw.x >> 16));
                    mkf[2] = bf2f((u16)(mraw.y & 0xffffu));
                    mkf[3] = bf2f((u16)(mraw.y >> 16));
                } else {
                    #pragma unroll
                    for (int r = 0; r < 4; ++r) {
                        const int m = m0 + r;
                        mkf[r] = (lv && m < TOK) ? mp[l * TOK + m] : 0.0f;
                    }
                }
                #pragma unroll
                for (int r = 0; r < 4; ++r) {
                    const int m = m0 + r;
                    float val = -1e30f;
                    if (lv && m < TOK) val = e[mi][ni][r] + bgv[r] + mkf[r];
                    e[mi][ni][r] = val;
                }
            }
            float mx = -1e30f;
            #pragma unroll
            for (int mi = 0; mi < 4; ++mi)
                #pragma unroll
                for (int r = 0; r < 4; ++r) mx = fmaxf(mx, e[mi][ni][r]);
            mx = fmaxf(mx, __shfl_xor(mx, 16));
            mx = fmaxf(mx, __shfl_xor(mx, 32));
            float s = 0.f;
            #pragma unroll
            for (int mi = 0; mi < 4; ++mi) {
                #pragma unroll
                for (int r = 0; r < 4; ++r) {
                    const float p = __expf(e[mi][ni][r] - mx);
                    e[mi][ni][r] = p;
                    s += p;
                }
            }
            s += __shfl_xor(s, 16);
            s += __shfl_xor(s, 32);
            const float rs = 1.0f / s;
            #pragma unroll
            for (int mi = 0; mi < 4; ++mi) pf[mi][ni] = pack4s(e[mi][ni], rs);
        }
    }

    // ================= phase 5: V projection (after e is dead) ===============
    s16x4 vf[4][2];  // [m-chunk][d-tile n]; C rows = tok = m
    {
        f32x4 acc[4][2];
        #pragma unroll
        for (int mi = 0; mi < 4; ++mi)
            #pragma unroll
            for (int n = 0; n < 2; ++n) acc[mi][n] = f32x4{0.f, 0.f, 0.f, 0.f};
        #pragma unroll
        for (int kk = 0; kk < 4; ++kk) {
            bf16x8 xa[4];
            #pragma unroll
            for (int mi = 0; mi < 4; ++mi) {
                int tok = mi * 16 + l16; tok = tok < TOK ? tok : TOK - 1;
                xa[mi] = cvt8(vp + tok * DIM + kk * 32 + k8 * 8);
            }
            bf16x8 wb[2];
            #pragma unroll
            for (int n = 0; n < 2; ++n)
                wb[n] = cvt8(Wv + (h * 32 + n * 16 + l16) * DIM + kk * 32 + k8 * 8);
            #pragma unroll
            for (int mi = 0; mi < 4; ++mi)
                #pragma unroll
                for (int n = 0; n < 2; ++n) acc[mi][n] = MFMA32(xa[mi], wb[n], acc[mi][n]);
        }
        #pragma unroll
        for (int mi = 0; mi < 4; ++mi)
            #pragma unroll
            for (int n = 0; n < 2; ++n) vf[mi][n] = pack4(acc[mi][n]);
    }

    // ================= phase 6: PV via MFMA16 (all lane-local) ===============
    f32x4 o_[4][2];  // C: row = l = ni*16 + k8*4 + r, col = d = h*32 + n*16 + l16
    #pragma unroll
    for (int ni = 0; ni < 4; ++ni) {
        #pragma unroll
        for (int n = 0; n < 2; ++n) {
            f32x4 c = {0.f, 0.f, 0.f, 0.f};
            #pragma unroll
            for (int mi = 0; mi < 4; ++mi) c = MFMA16(pf[mi][ni], vf[mi][n], c);
            o_[ni][n] = c;
        }
    }
    // pf/vf dead here.

    // ================= phase 7: OH[l][d] <- O; Wo loads overlap barrier ======
    #pragma unroll
    for (int ni = 0; ni < 4; ++ni) {
        #pragma unroll
        for (int n = 0; n < 2; ++n) {
            const int d = h * 32 + n * 16 + l16;
            #pragma unroll
            for (int r = 0; r < 4; ++r) {
                const int row = ni * 16 + k8 * 4 + r;
                *reinterpret_cast<u16*>(OH + xo256(row, d * 2)) = bfbits(o_[ni][n][r]);
            }
        }
    }
    bf16x8 aw[2][4];  // Wo A-frags: loaded here so HBM/L2 latency hides under barrier
    #pragma unroll
    for (int m2 = 0; m2 < 2; ++m2) {
        const int o = (wave * 2 + m2) * 16 + l16;
        #pragma unroll
        for (int kk = 0; kk < 4; ++kk)
            aw[m2][kk] = cvt8(Wo + o * DIM + kk * 32 + k8 * 8);
    }
    __syncthreads();

    // ================= phase 8: out-proj swapped: out^T[o][l], float4 store ==
    #pragma unroll
    for (int ni = 0; ni < 4; ++ni) {
        const int l = ni * 16 + l16;
        bf16x8 bx[4];
        #pragma unroll
        for (int kk = 0; kk < 4; ++kk)
            bx[kk] = *reinterpret_cast<const bf16x8*>(OH + xo256(l, kk * 64 + k8 * 16));
        #pragma unroll
        for (int m2 = 0; m2 < 2; ++m2) {
            f32x4 c = {0.f, 0.f, 0.f, 0.f};
            #pragma unroll
            for (int kk = 0; kk < 4; ++kk) c = MFMA32(aw[m2][kk], bx[kk], c);
            if (l < TOK) {
                const int o0 = (wave * 2 + m2) * 16 + k8 * 4;
                const float4 bias = *reinterpret_cast<const float4*>(bo + o0);
                float4 st;
                st.x = c[0] + bias.x;
                st.y = c[1] + bias.y;
                st.z = c[2] + bias.z;
                st.w = c[3] + bias.w;
                *reinterpret_cast<float4*>(op + l * DIM + o0) = st;
            }
        }
    }
}

extern "C" void kernel_launch(void* const* d_in, const int* in_sizes, int n_in,
                              void* d_out, int out_size, void* d_ws, size_t ws_size,
                              hipStream_t stream) {
    const float* q    = (const float*)d_in[0];
    const float* k    = (const float*)d_in[1];
    const float* v    = (const float*)d_in[2];
    const float* mask = (const float*)d_in[3];
    const float* Wq   = (const float*)d_in[4];
    const float* Wk   = (const float*)d_in[5];
    const float* Wv   = (const float*)d_in[6];
    const float* Wo   = (const float*)d_in[7];
    const float* bo   = (const float*)d_in[8];
    const float* rel  = (const float*)d_in[9];
    float* out = (float*)d_out;

    const int B = in_sizes[0] / (TOK * DIM);  // 8192 windows
    const size_t MASK_BYTES = (size_t)NWIN * 64 * 64 * sizeof(u16);    // 8388608
    const size_t BIAS_BYTES = (size_t)NHEAD * 64 * 64 * sizeof(float); // 65536

    if (ws_size >= MASK_BYTES + BIAS_BYTES) {
        u16* mtbl = (u16*)d_ws;
        float* btbl = (float*)((char*)d_ws + MASK_BYTES);
        mask_pre_kernel<<<dim3(NWIN * 64 * 64 / 256), dim3(256), 0, stream>>>(mask, mtbl);
        bias_pre_kernel<<<dim3(NHEAD * 64 * 64 / 256), dim3(256), 0, stream>>>(rel, btbl);
        winattn_kernel<0><<<dim3(B), dim3(256), 0, stream>>>(q, k, v, mask, Wq, Wk, Wv, Wo,
                                                             bo, mtbl, btbl, out);
    } else {
        float* btbl = (float*)d_ws;  // 64 KB, proven to fit
        bias_pre_kernel<<<dim3(NHEAD * 64 * 64 / 256), dim3(256), 0, stream>>>(rel, btbl);
        winattn_kernel<1><<<dim3(B), dim3(256), 0, stream>>>(q, k, v, mask, Wq, Wk, Wv, Wo,
                                                             bo, nullptr, btbl, out);
    }
}